// Round 12
// baseline (367.553 us; speedup 1.0000x reference)
//
#include <hip/hip_runtime.h>
#include <hip/hip_bf16.h>

#define BB 4
#define HH 16
#define LL 2048
#define DD 64
#define EE 1024
#define MM (BB*LL)   // 8192 rows
#define SCL 0.125f
#define L2E 1.44269504f

using bf16   = __hip_bfloat16;
using bf16x8 = __attribute__((ext_vector_type(8))) __bf16;
using s16x4  = __attribute__((ext_vector_type(4))) short;
using f32x4  = __attribute__((ext_vector_type(4))) float;
using u32x4  = __attribute__((ext_vector_type(4))) unsigned int;
typedef unsigned int u32;

// ---- dtype-polymorphic helpers (verified R2/R4) ----
__device__ __forceinline__ bf16x8 ld8(const bf16* p){ return *(const bf16x8*)p; }
__device__ __forceinline__ bf16x8 ld8(const float* p){
  u32x4 a = *(const u32x4*)p;
  u32x4 b = *(const u32x4*)(p + 4);
  union { bf16x8 v; unsigned short s[8]; } r;
#pragma unroll
  for (int i = 0; i < 4; i++) r.s[i]     = (unsigned short)((a[i] + 0x7FFFu + ((a[i] >> 16) & 1u)) >> 16);
#pragma unroll
  for (int i = 0; i < 4; i++) r.s[i + 4] = (unsigned short)((b[i] + 0x7FFFu + ((b[i] >> 16) & 1u)) >> 16);
  return r.v;
}
__device__ __forceinline__ float ldf(const bf16* p){ return __bfloat162float(*p); }
__device__ __forceinline__ float ldf(const float* p){ return *p; }
__device__ __forceinline__ bf16 to_b(bf16 v){ return v; }
__device__ __forceinline__ bf16 to_b(float v){ return __float2bfloat16(v); }

// scale 8 bf16 by 2^-3 (exact: float round-trip only shifts exponent)
__device__ __forceinline__ bf16x8 scl8(bf16x8 v){
  union { bf16x8 v; unsigned short s[8]; } a, r;
  a.v = v;
#pragma unroll
  for (int i = 0; i < 8; i++) {
    bf16 b; *(unsigned short*)&b = a.s[i];
    bf16 c = __float2bfloat16(__bfloat162float(b) * 0.125f);
    r.s[i] = *(unsigned short*)&c;
  }
  return r.v;
}

// async global->LDS, 16B/lane; LDS dest = wave-uniform base + lane*16 (m97/m104)
__device__ __forceinline__ void async16(const bf16* g, bf16* l) {
  __builtin_amdgcn_global_load_lds((const __attribute__((address_space(1))) u32*)g,
                                   (__attribute__((address_space(3))) u32*)l, 16, 0, 0);
}

// ---- dtype detect (verified R2/R4) ----
__global__ __launch_bounds__(256) void detect_dtype(const unsigned int* __restrict__ w,
                                                    int* __restrict__ flag) {
  __shared__ int cnt[256];
  int tid = threadIdx.x;
  int c = 0;
  for (int i = 0; i < 16; i++) {
    unsigned u = w[tid * 16 + i];
    unsigned e = (u >> 7) & 0xFF;
    c += (e >= 100 && e <= 140) ? 1 : 0;
  }
  cnt[tid] = c;
  __syncthreads();
  for (int s = 128; s > 0; s >>= 1) {
    if (tid < s) cnt[tid] += cnt[tid + s];
    __syncthreads();
  }
  if (tid == 0) *flag = (cnt[0] > 2048) ? 1 : 0;   // 1 = bf16 inputs
}

// ---- input pre-convert: Q/K/V -> bf16 workspace (copy if already bf16) ----
__global__ __launch_bounds__(256) void convert_in(
    const void* __restrict__ X0, const void* __restrict__ X1, const void* __restrict__ X2,
    bf16* __restrict__ Y0, bf16* __restrict__ Y1, bf16* __restrict__ Y2,
    const int* __restrict__ flag) {
  int z = blockIdx.z;
  const void* X = (z == 0) ? X0 : (z == 1) ? X1 : X2;
  bf16* Y       = (z == 0) ? Y0 : (z == 1) ? Y1 : Y2;
  size_t idx = ((size_t)blockIdx.x * 256 + threadIdx.x) * 8;
  if (*flag) *(bf16x8*)(Y + idx) = *(const bf16x8*)((const bf16*)X + idx);
  else       *(bf16x8*)(Y + idx) = ld8((const float*)X + idx);
}

// ---------------- fused weight transposes: Wt[n][k] = bf16(W[k][n]) ----------------
template<typename T>
__device__ __forceinline__ void tr_body(const T* __restrict__ W, bf16* __restrict__ Wt,
                                        bf16 (*t)[33]) {
  int tx = threadIdx.x, ty = threadIdx.y;            // block (32,8)
  int x = blockIdx.x * 32 + tx;
  for (int r = 0; r < 4; r++)
    t[ty + r * 8][tx] = to_b(W[(blockIdx.y * 32 + ty + r * 8) * EE + x]);
  __syncthreads();
  int x2 = blockIdx.y * 32 + tx;
  for (int r = 0; r < 4; r++)
    Wt[(blockIdx.x * 32 + ty + r * 8) * EE + x2] = t[tx][ty + r * 8];
}

__global__ __launch_bounds__(256) void transpose_w4(
    const void* __restrict__ W0, const void* __restrict__ W1,
    const void* __restrict__ W2, const void* __restrict__ W3,
    bf16* __restrict__ T0, bf16* __restrict__ T1,
    bf16* __restrict__ T2, bf16* __restrict__ T3,
    const int* __restrict__ flag) {
  __shared__ bf16 t[32][33];
  int z = blockIdx.z;
  const void* W = (z == 0) ? W0 : (z == 1) ? W1 : (z == 2) ? W2 : W3;
  bf16* Wt      = (z == 0) ? T0 : (z == 1) ? T1 : (z == 2) ? T2 : T3;
  if (*flag) tr_body<bf16>((const bf16*)W, Wt, t);
  else       tr_body<float>((const float*)W, Wt, t);
}

// ---------------- 128x128 GEMM, BK=32, linear LDS (0-conflict, R1-verified), ----------
// ---------------- double-buffered 2-phase pipeline, operand-swap epilogue  ----------
// (verified R5: qkv/out dropped out of top-5; unchanged this round)
#define TILE_A (128 * 32)
template<typename TIO, bool SW>
__device__ void gemm_body(const bf16* __restrict__ A, const bf16* __restrict__ Bt,
                          const TIO* __restrict__ bias, void* __restrict__ Cv,
                          int mode, bf16* As, bf16* Bs) {
  constexpr int K = EE;
  int tid = threadIdx.x;
  int lane = tid & 63, w = tid >> 6;
  int l16 = lane & 15, quad = lane >> 4;
  int linear = blockIdx.x + 8 * blockIdx.y;      // grid (8,64[,z])
  int xcd = linear & 7;
  int slot = linear >> 3;
  int m0 = (xcd * 8 + (slot & 7)) * 128;         // m-tile
  int n0 = (slot >> 3) * 128;                    // n-tile
  int mw = (w & 1) * 64;
  int nw = (w >> 1) * 64;
  int lr = lane >> 2;            // staging row within 16-row group (32-col rows)
  int lc = (lane & 3) * 8;       // staging col (elements)

  f32x4 acc[4][4] = {};

  auto stage = [&](bf16* Ad, bf16* Bd, int k0) {
#pragma unroll
    for (int s = 0; s < 2; s++) {
      int r = w * 32 + s * 16;
      async16(A  + (size_t)(m0 + r + lr) * K + k0 + lc, Ad + r * 32);
      async16(Bt + (size_t)(n0 + r + lr) * K + k0 + lc, Bd + r * 32);
    }
  };

  auto compute = [&](const bf16* Ab, const bf16* Bb) {
    bf16x8 af[4], bfr[4];
#pragma unroll
    for (int t = 0; t < 4; t++) {
      af[t]  = *(const bf16x8*)(Ab + (mw + t * 16 + l16) * 32 + quad * 8);
      bfr[t] = *(const bf16x8*)(Bb + (nw + t * 16 + l16) * 32 + quad * 8);
    }
#pragma unroll
    for (int mt = 0; mt < 4; mt++)
#pragma unroll
      for (int nt = 0; nt < 4; nt++) {
        if (SW)
          acc[mt][nt] = __builtin_amdgcn_mfma_f32_16x16x32_bf16(bfr[nt], af[mt], acc[mt][nt], 0, 0, 0);
        else
          acc[mt][nt] = __builtin_amdgcn_mfma_f32_16x16x32_bf16(af[mt], bfr[nt], acc[mt][nt], 0, 0, 0);
      }
  };

  // prologue: stage tile 0 into buf0, full drain, everyone synced
  stage(As, Bs, 0);
  asm volatile("s_waitcnt vmcnt(0)" ::: "memory");
  __builtin_amdgcn_s_barrier();
  asm volatile("" ::: "memory");

  // 32 K-tiles, 2 per iteration -> static double-buffer addressing
#pragma unroll 1
  for (int t = 0; t < K / 32; t += 2) {
    stage(As + TILE_A, Bs + TILE_A, t * 32 + 32);   // prefetch t+1 -> buf1
    compute(As, Bs);                                // tile t from buf0
    asm volatile("s_waitcnt vmcnt(0)" ::: "memory");
    __builtin_amdgcn_s_barrier();
    asm volatile("" ::: "memory");
    if (t + 2 < K / 32)
      stage(As, Bs, t * 32 + 64);                   // prefetch t+2 -> buf0
    compute(As + TILE_A, Bs + TILE_A);              // tile t+1 from buf1
    asm volatile("s_waitcnt vmcnt(0)" ::: "memory");
    __builtin_amdgcn_s_barrier();
    asm volatile("" ::: "memory");
  }

  if (SW) {
    // D-frag: row m = m0+mw+mt*16+l16 ; cols n = n0+nw+nt*16+quad*4+i (4 consecutive)
#pragma unroll
    for (int mt = 0; mt < 4; mt++) {
      int row = m0 + mw + mt * 16 + l16;
#pragma unroll
      for (int nt = 0; nt < 4; nt++) {
        int colb = n0 + nw + nt * 16 + quad * 4;
        f32x4 v = acc[mt][nt];
        if (mode == 0) {
          union { s16x4 v4; bf16 e[4]; } u;
#pragma unroll
          for (int i = 0; i < 4; i++) u.e[i] = __float2bfloat16(v[i] + ldf(bias + colb + i));
          *(s16x4*)((bf16*)Cv + (size_t)row * EE + colb) = u.v4;
        } else {  // mode 3: final output, dtype = TIO
          if constexpr (__is_same(TIO, bf16)) {
            union { s16x4 v4; bf16 e[4]; } u;
#pragma unroll
            for (int i = 0; i < 4; i++) u.e[i] = __float2bfloat16(v[i] + ldf(bias + colb + i));
            *(s16x4*)((bf16*)Cv + (size_t)row * EE + colb) = u.v4;
          } else {
            f32x4 fv;
#pragma unroll
            for (int i = 0; i < 4; i++) fv[i] = v[i] + ldf(bias + colb + i);
            *(f32x4*)((float*)Cv + (size_t)row * EE + colb) = fv;
          }
        }
      }
    }
  } else {
    // mode 2: V^T [B,H,D,L]; D-frag row m = quad*4+i (4 consecutive l) -> 8B store
#pragma unroll
    for (int nt = 0; nt < 4; nt++) {
      int col = n0 + nw + nt * 16 + l16;
      float bv = ldf(bias + col);
      int hh = col >> 6, d = col & 63;
#pragma unroll
      for (int mt = 0; mt < 4; mt++) {
        f32x4 v = acc[mt][nt];
        int rowb = m0 + mw + mt * 16 + quad * 4;
        int b = rowb >> 11, l0 = rowb & 2047;
        union { s16x4 p; bf16 e[4]; } u;
#pragma unroll
        for (int i = 0; i < 4; i++) u.e[i] = __float2bfloat16(v[i] + bv);
        *(s16x4*)((bf16*)Cv + ((size_t)(b * HH + hh) * DD + d) * LL + l0) = u.p;
      }
    }
  }
}

__global__ __launch_bounds__(256) void qkv_gemm(
    const bf16* __restrict__ Qc, const bf16* __restrict__ Kc, const bf16* __restrict__ Vc,
    const bf16* __restrict__ WQt, const bf16* __restrict__ WKt, const bf16* __restrict__ WVt,
    const void* __restrict__ bQ, const void* __restrict__ bK, const void* __restrict__ bV,
    bf16* __restrict__ qo, bf16* __restrict__ ko, bf16* __restrict__ vo,
    const int* __restrict__ flag) {
  __shared__ __align__(16) bf16 As[2 * TILE_A];
  __shared__ __align__(16) bf16 Bs[2 * TILE_A];
  int z = blockIdx.z;
  const bf16* A    = (z == 0) ? Qc  : (z == 1) ? Kc  : Vc;
  const bf16* Bt   = (z == 0) ? WQt : (z == 1) ? WKt : WVt;
  const void* bb   = (z == 0) ? bQ  : (z == 1) ? bK  : bV;
  bf16* C          = (z == 0) ? qo  : (z == 1) ? ko  : vo;
  if (z == 2) {
    if (*flag) gemm_body<bf16,  false>(A, Bt, (const bf16*)bb,  C, 2, As, Bs);
    else       gemm_body<float, false>(A, Bt, (const float*)bb, C, 2, As, Bs);
  } else {
    if (*flag) gemm_body<bf16,  true>(A, Bt, (const bf16*)bb,  C, 0, As, Bs);
    else       gemm_body<float, true>(A, Bt, (const float*)bb, C, 0, As, Bs);
  }
}

__global__ __launch_bounds__(256) void out_gemm(const bf16* __restrict__ A,
                                                const bf16* __restrict__ WOt,
                                                const void* __restrict__ bO,
                                                void* __restrict__ C,
                                                const int* __restrict__ flag) {
  __shared__ __align__(16) bf16 As[2 * TILE_A];
  __shared__ __align__(16) bf16 Bs[2 * TILE_A];
  if (*flag) gemm_body<bf16,  true>(A, WOt, (const bf16*)bO,  C, 3, As, Bs);
  else       gemm_body<float, true>(A, WOt, (const float*)bO, C, 3, As, Bs);
}

// ---------------- flash attention, causal, S^T formulation ----------------
// q,k: [B,L,E] bf16 (head offset h*64, row stride E)   v: [B,H,D,L] bf16   out: [B,L,E] bf16
// R10/R12: 3-deep K/V pipeline with COUNTED vmcnt (T4). R9 showed attn latency-bound:
// T_iter ~1500-2000cyc vs ~450cyc compute -> exposed K/V load latency (1-step dbuf
// gives only ~500cyc issue->use distance < HBM ~900cyc; ~2 blocks/CU TLP can't hide).
// Now: stage(kb+2) each body -> tile loads issued 2 bodies (~1000+cyc) before use;
// s_waitcnt vmcnt(4) (counted, 4 loads/wave/tile) + raw s_barrier per body; vmcnt(0)
// only in the 2 tail bodies (nothing else in flight). 48KB LDS -> 3 blocks/CU.
// Softmax: static-max (R9-verified), zero cross-lane ops in the k-loop.
__global__ __launch_bounds__(256) void attn(const bf16* __restrict__ qg,
                                            const bf16* __restrict__ kg,
                                            const bf16* __restrict__ vg,
                                            bf16* __restrict__ outg) {
  __shared__ __align__(16) bf16 Ks[3][64 * 64];
  __shared__ __align__(16) bf16 Vs[3][64 * 64];
  int linear = blockIdx.x + 16 * blockIdx.y;     // grid (16,64)
  int xcd = linear & 7;
  int slot = linear >> 3;                        // 0..127
  int bh = xcd * 8 + (slot & 7);                 // head-batch index, 8 per XCD
  int pb = slot >> 3;                            // 0..15; handles tiles pb and 31-pb
  int tid = threadIdx.x;
  int w = tid >> 6, lane = tid & 63, l16 = lane & 15, quad = lane >> 4;
  int b = bh >> 4, hh = bh & 15;

  const bf16* qp = qg + (size_t)b * LL * EE + hh * DD;
  const bf16* kp = kg + (size_t)b * LL * EE + hh * DD;
  const bf16* vp = vg + (size_t)bh * DD * LL;
  const f32x4 z4 = {};
  int x7 = l16 & 7;                  // read-side swizzle key (row&7 == l16&7 for our rows)
  int gb = (lane & 7) ^ (lane >> 3); // staging swizzle: r&7 == lane>>3 for our rows

  for (int half = 0; half < 2; half++) {
    int tile = half ? (31 - pb) : pb;
    int qrow0 = tile * 64 + w * 16;
    int q = qrow0 + l16;
    bf16x8 bq0 = scl8(*(const bf16x8*)(qp + (size_t)q * EE + quad * 8));
    bf16x8 bq1 = scl8(*(const bf16x8*)(qp + (size_t)q * EE + 32 + quad * 8));

    float l = 0.f;                   // per-lane partial denominator (static-max)
    f32x4 o[4] = {};
    int kend = tile + 1;             // uniform across the block's 4 waves

    // running per-lane prefetch pointers (advance by one tile each stage)
    const bf16* kP[2];
    const bf16* vP[2];
#pragma unroll
    for (int t = 0; t < 2; t++) {
      int r = w * 16 + t * 8 + (lane >> 3);
      kP[t] = kp + (size_t)r * EE + gb * 8;
      vP[t] = vp + (size_t)r * LL + gb * 8;
    }

    auto stageKV = [&](bf16* Kd, bf16* Vd) {
#pragma unroll
      for (int t = 0; t < 2; t++) {
        int R = w * 16 + t * 8;
        async16(kP[t], Kd + R * 64);
        async16(vP[t], Vd + R * 64);
        kP[t] += (size_t)64 * EE;
        vP[t] += 64;
      }
    };

    __syncthreads();                 // protect buf0 from previous half's readers
    // prologue: stage tiles 0,1 into bufs 0,1 (3-deep pipeline)
    stageKV(&Ks[0][0], &Vs[0][0]);
    if (kend > 1) {
      stageKV(&Ks[1][0], &Vs[1][0]);
      asm volatile("s_waitcnt vmcnt(4)" ::: "memory");   // tile0 landed, tile1 in flight
    } else {
      asm volatile("s_waitcnt vmcnt(0)" ::: "memory");
    }
    __builtin_amdgcn_s_barrier();
    asm volatile("" ::: "memory");

    auto body = [&](int kb, const bf16* Kb, const bf16* Vb, bf16* KsN, bf16* VsN) {
      int kbase = kb * 64;
      bool pf = (kb + 2 < kend);
      if (pf) stageKV(KsN, VsN);     // issue tile kb+2 -> lands 2 bodies from now

      // ---- S^T = K·Q^T: A = K rows (from LDS), B = Q rows; C frag: row=key, col=q ----
      f32x4 s[4];
      __builtin_amdgcn_s_setprio(1);
#pragma unroll
      for (int kt = 0; kt < 4; kt++) {
        int row = kt * 16 + l16;
        bf16x8 kf0 = *(const bf16x8*)(Kb + row * 64 + (quad ^ x7) * 8);
        bf16x8 kf1 = *(const bf16x8*)(Kb + row * 64 + ((quad + 4) ^ x7) * 8);
        s[kt] = __builtin_amdgcn_mfma_f32_16x16x32_bf16(kf0, bq0, z4, 0, 0, 0);
        s[kt] = __builtin_amdgcn_mfma_f32_16x16x32_bf16(kf1, bq1, s[kt], 0, 0, 0);
      }
      __builtin_amdgcn_s_setprio(0);
#if __has_builtin(__builtin_amdgcn_mfma_f32_16x16x16bf16_1k)
      s16x4 vf[4][4];   // V^T A-frags: A[m=d=l16][k=key=quad*4+j]
#pragma unroll
      for (int j = 0; j < 4; j++)
#pragma unroll
        for (int kt = 0; kt < 4; kt++)
          vf[j][kt] = *(const s16x4*)(Vb + (j * 16 + l16) * 64 +
                                      ((kt * 2 + (quad >> 1)) ^ x7) * 8 + (quad & 1) * 4);
#endif
      // ---- static-max softmax: p = exp2(s*L2E), mask -> 0; no cross-lane ops ----
      float p[16];
      if (kbase + 63 <= qrow0) {
#pragma unroll
        for (int kt = 0; kt < 4; kt++)
#pragma unroll
          for (int i = 0; i < 4; i++) {
            float pv = exp2f(s[kt][i] * L2E);
            p[kt * 4 + i] = pv;
            l += pv;
          }
      } else {
        int rel = q - kbase - quad * 4;
#pragma unroll
        for (int kt = 0; kt < 4; kt++)
#pragma unroll
          for (int i = 0; i < 4; i++) {
            float pv = (kt * 16 + i <= rel) ? exp2f(s[kt][i] * L2E) : 0.f;
            p[kt * 4 + i] = pv;
            l += pv;
          }
      }
      // ---- P^T pack (packed cvt): C-layout == B-operand layout of 16x16x16 MFMA ----
      union { s16x4 v4; unsigned u[2]; } pk[4];
#pragma unroll
      for (int kt = 0; kt < 4; kt++) {
        __hip_bfloat162 h0 = __float22bfloat162_rn(float2{p[kt * 4 + 0], p[kt * 4 + 1]});
        __hip_bfloat162 h1 = __float22bfloat162_rn(float2{p[kt * 4 + 2], p[kt * 4 + 3]});
        __builtin_memcpy(&pk[kt].u[0], &h0, 4);
        __builtin_memcpy(&pk[kt].u[1], &h1, 4);
      }
#if __has_builtin(__builtin_amdgcn_mfma_f32_16x16x16bf16_1k)
      __builtin_amdgcn_s_setprio(1);
#pragma unroll
      for (int kt = 0; kt < 4; kt++)
#pragma unroll
        for (int j = 0; j < 4; j++)
          o[j] = __builtin_amdgcn_mfma_f32_16x16x16bf16_1k(vf[j][kt], pk[kt].v4, o[j], 0, 0, 0);
      __builtin_amdgcn_s_setprio(0);
#else
#pragma unroll
      for (int c = 0; c < 2; c++) {
        union { bf16x8 v8; unsigned u[4]; } bfr;
#pragma unroll
        for (int r = 0; r < 4; r++) {
          int key = c * 32 + quad * 8 + 2 * r;
          int srcl = (((key >> 2) & 3) << 4) + l16;
          unsigned v0 = __shfl((int)pk[2 * c].u[r & 1], srcl, 64);
          unsigned v1 = __shfl((int)pk[2 * c + 1].u[r & 1], srcl, 64);
          bfr.u[r] = (quad < 2) ? v0 : v1;
        }
        __builtin_amdgcn_s_setprio(1);
#pragma unroll
        for (int j = 0; j < 4; j++) {
          bf16x8 vfr = *(const bf16x8*)(Vb + (j * 16 + l16) * 64 + ((c * 4 + quad) ^ x7) * 8);
          o[j] = __builtin_amdgcn_mfma_f32_16x16x32_bf16(vfr, bfr.v8, o[j], 0, 0, 0);
        }
        __builtin_amdgcn_s_setprio(0);
      }
#endif
      // counted drain: tile kb+1's 4 loads are the oldest still outstanding
      if (pf) asm volatile("s_waitcnt vmcnt(4)" ::: "memory");
      else    asm volatile("s_waitcnt vmcnt(0)" ::: "memory");
      __builtin_amdgcn_s_barrier();
      asm volatile("" ::: "memory");
    };

    // 3x-unrolled kb loop: static buffer pointers, compute (kb%3), stage ((kb+2)%3)
    int kb = 0;
    for (;;) {
      body(kb, &Ks[0][0], &Vs[0][0], &Ks[2][0], &Vs[2][0]); if (++kb >= kend) break;
      body(kb, &Ks[1][0], &Vs[1][0], &Ks[0][0], &Vs[0][0]); if (++kb >= kend) break;
      body(kb, &Ks[2][0], &Vs[2][0], &Ks[1][0], &Vs[1][0]); if (++kb >= kend) break;
    }

    // ---- deferred cross-quad l-reduce (once per q-tile, not per k-iter) ----
    l += __shfl_xor(l, 16);
    l += __shfl_xor(l, 32);

    // ---- epilogue: O^T frag (d = j*16+quad*4+i, q = l16), 8B packed stores ----
    float inv = 1.0f / l;
#pragma unroll
    for (int j = 0; j < 4; j++) {
      union { s16x4 v4; bf16 e[4]; } u;
#pragma unroll
      for (int i = 0; i < 4; i++) u.e[i] = __float2bfloat16(o[j][i] * inv);
      *(s16x4*)(outg + (size_t)(b * LL + q) * EE + hh * DD + j * 16 + quad * 4) = u.v4;
    }
  }
}

extern "C" void kernel_launch(void* const* d_in, const int* in_sizes, int n_in,
                              void* d_out, int out_size, void* d_ws, size_t ws_size,
                              hipStream_t stream) {
  const void* Q   = d_in[0];
  const void* Kin = d_in[1];
  const void* V   = d_in[2];
  const void* WQ  = d_in[3];
  const void* bQ  = d_in[4];
  const void* WK  = d_in[5];
  const void* bK  = d_in[6];
  const void* WV  = d_in[7];
  const void* bV  = d_in[8];
  const void* WO  = d_in[9];
  const void* bO  = d_in[10];

  int* flag = (int*)d_ws;
  bf16* base = (bf16*)((char*)d_ws + 256);
  bf16* wqt  = base;                        // 4 x 1024^2 bf16
  bf16* wkt  = wqt + (size_t)EE * EE;
  bf16* wvt  = wkt + (size_t)EE * EE;
  bf16* wot  = wvt + (size_t)EE * EE;
  bf16* Qc   = wot + (size_t)EE * EE;       // converted inputs, [B,L,E] bf16
  bf16* Kc   = Qc  + (size_t)MM * EE;
  bf16* Vc   = Kc  + (size_t)MM * EE;
  bf16* qws  = Vc  + (size_t)MM * EE;       // projected q  [B,L,E]
  bf16* kws  = qws + (size_t)MM * EE;       // projected k  [B,L,E]
  bf16* vws  = kws + (size_t)MM * EE;       // projected v  [B,H,D,L]
  bf16* aout = vws + (size_t)MM * EE;       // attention out [B,L,E]

  detect_dtype<<<1, 256, 0, stream>>>((const unsigned int*)WQ, flag);

  convert_in<<<dim3(MM * EE / 8 / 256, 1, 3), 256, 0, stream>>>(Q, Kin, V, Qc, Kc, Vc, flag);

  transpose_w4<<<dim3(32, 32, 4), dim3(32, 8), 0, stream>>>(
      WQ, WK, WV, WO, wqt, wkt, wvt, wot, flag);

  qkv_gemm<<<dim3(8, 64, 3), 256, 0, stream>>>(
      Qc, Kc, Vc, wqt, wkt, wvt, bQ, bK, bV, qws, kws, vws, flag);

  attn<<<dim3(16, 64), 256, 0, stream>>>(qws, kws, vws, aout);

  out_gemm<<<dim3(8, 64), 256, 0, stream>>>(aout, wot, bO, d_out, flag);
}